// Round 12
// baseline (251.923 us; speedup 1.0000x reference)
//
#include <hip/hip_runtime.h>

typedef _Float16 half8  __attribute__((ext_vector_type(8)));
typedef _Float16 half2T __attribute__((ext_vector_type(2)));
typedef float    vfloat4 __attribute__((ext_vector_type(4)));

#define T_LEN 512
#define B_SZ  64
#define K_IN  868
#define KP    896            // 7 * 128, zero padded
#define E_DIM 100
#define M_TOT (T_LEN * B_SZ) // 32768, m = b*512 + t (b-major)

// ws layout (bytes). b-major: xp[m*128 + n], m = b*512 + t
#define WT_BYTES   (128 * KP * 2)          // 229376 : f16 Wt[128][896], [n][k]
#define BIAS_OFF   WT_BYTES                // f32 bias[128] (b_ih + b_hh, fwd|bwd)
#define XP_OFF     (BIAS_OFF + 512)        // f32 xp[32768][128]
#define XP_BYTES   ((size_t)M_TOT * 128 * 4)
#define HS_OFF     (XP_OFF + XP_BYTES)     // f32 hs[32768][128]

// async 16B global->LDS (no VGPR round-trip). LDS dest must be
// wave-uniform-base + lane*16 (m104) — callers pass exactly that.
__device__ __forceinline__ void gl_lds16(const void* g, void* l) {
#if __has_builtin(__builtin_amdgcn_global_load_lds)
    __builtin_amdgcn_global_load_lds(
        (const __attribute__((address_space(1))) void*)g,
        (__attribute__((address_space(3))) void*)l, 16, 0, 0);
#else
    *(float4*)l = *(const float4*)g;   // sync fallback, still correct
#endif
}

// ---------------------------------------------------------------- prep ----
__global__ __launch_bounds__(128) void prep_kernel(
    const float* __restrict__ Wf, const float* __restrict__ Wb,
    const float* __restrict__ bif, const float* __restrict__ bhf,
    const float* __restrict__ bib, const float* __restrict__ bhb,
    _Float16* __restrict__ Wt, float* __restrict__ bias)
{
    const int n = blockIdx.y;                       // 0..127 output channel
    const int k = blockIdx.x * 128 + threadIdx.x;   // 0..895
    float v = 0.f;
    if (k < K_IN) v = (n < 64) ? Wf[n * K_IN + k] : Wb[(n - 64) * K_IN + k];
    Wt[n * KP + k] = (_Float16)v;
    if (blockIdx.x == 0 && threadIdx.x == 0)
        bias[n] = (n < 64) ? (bif[n] + bhf[n]) : (bib[n - 64] + bhb[n - 64]);
}

// ---------------------------------------------------------------- GEMM ----
// BM=64 tile.  A staged as F16 (16 KB, sync convert — cheap VALU, validated
// R1-R7) + B 32 KB via async DMA = 48 KB LDS -> 3 blocks/CU, so two other
// blocks' work covers each chunk's barrier drain (duty-cycle fix; R11 was
// 64 KB -> 2 blocks/CU at ~50% duty).  XOR swizzle: logical 16B block
// bl = bp ^ (row&7) stored at physical bp (A via write addressing, B via
// lane->global-address permutation since DMA is lane-ordered).
__global__ __launch_bounds__(256) void gemm_kernel(
    const float* __restrict__ inputs, const int* __restrict__ pos,
    const float* __restrict__ emb, const _Float16* __restrict__ Wt,
    const float* __restrict__ bias, float* __restrict__ xp)
{
    __shared__ _Float16 Ah[64 * 128];     // 16 KB
    __shared__ _Float16 Bh[128 * 128];    // 32 KB

    const int tid  = threadIdx.x;
    const int mb   = blockIdx.x;         // 0..511 (64-row M tiles)
    const int w    = tid >> 6;           // wave 0..3
    const int lane = tid & 63;
    const int q    = lane >> 4;          // quad 0..3
    const int lr   = lane & 15;
    const int rsw  = lr & 7;
    const int wm   = w >> 1;             // wave covers 32 rows x 64 cols of C
    const int wn   = w & 1;

    vfloat4 acc[2][4];
#pragma unroll
    for (int i = 0; i < 2; ++i)
#pragma unroll
        for (int j = 0; j < 4; ++j) { vfloat4 z = {0.f, 0.f, 0.f, 0.f}; acc[i][j] = z; }

    const float* Ag = inputs + (size_t)(mb * 64) * 768;

    for (int kc = 0; kc < 7; ++kc) {
        // B first: async DMA queue fills while we do A's sync convert
        // B: 32 KB f16 = 2048 16B slots, 8 async instrs/wave
#pragma unroll
        for (int i = 0; i < 8; ++i) {
            const int slot = (i * 4 + w) * 64 + lane;       // 0..2047
            const int row  = slot >> 4;                     // 0..127
            const int bp   = slot & 15;
            const int bl   = bp ^ (row & 7);
            gl_lds16(Wt + (size_t)row * KP + kc * 128 + bl * 8,
                     (char*)Bh + slot * 16);
        }

        // A: 16 KB f16 = 1024 16B slots, 4 per thread, sync load+convert
#pragma unroll
        for (int it = 0; it < 4; ++it) {
            const int slot = it * 256 + tid;                // 0..1023
            const int row  = slot >> 4;                     // 0..63
            const int bp   = slot & 15;
            const int bl   = bp ^ (row & 7);
            half8 av;
            if (kc < 6) {
                const float* src = Ag + (size_t)row * 768 + kc * 128 + bl * 8;
                const vfloat4 lo = *(const vfloat4*)(src);
                const vfloat4 hi = *(const vfloat4*)(src + 4);
                av[0] = (_Float16)lo[0]; av[1] = (_Float16)lo[1];
                av[2] = (_Float16)lo[2]; av[3] = (_Float16)lo[3];
                av[4] = (_Float16)hi[0]; av[5] = (_Float16)hi[1];
                av[6] = (_Float16)hi[2]; av[7] = (_Float16)hi[3];
            } else {
                const int p = pos[mb * 64 + row];
                const float* er = emb + (size_t)p * E_DIM;
                const int c0 = bl * 8;
#pragma unroll
                for (int e = 0; e < 8; ++e) {
                    const int c = c0 + e;
                    av[e] = (_Float16)((c < E_DIM) ? er[c] : 0.f);
                }
            }
            *(half8*)&Ah[slot * 8] = av;
        }
        __syncthreads();   // drains DMA (vmcnt) + A ds_writes

#pragma unroll
        for (int s = 0; s < 4; ++s) {
            const int cbr = (s << 2) | q;
            half8 af[2], bf[4];
#pragma unroll
            for (int mt = 0; mt < 2; ++mt) {
                const int row = wm * 32 + mt * 16 + lr;     // row&7 == rsw
                af[mt] = *(const half8*)&Ah[row * 128 + ((cbr ^ rsw) << 3)];
            }
#pragma unroll
            for (int nt = 0; nt < 4; ++nt) {
                const int row = wn * 64 + nt * 16 + lr;
                bf[nt] = *(const half8*)&Bh[row * 128 + ((cbr ^ rsw) << 3)];
            }
#pragma unroll
            for (int mt = 0; mt < 2; ++mt)
#pragma unroll
                for (int nt = 0; nt < 4; ++nt)
                    acc[mt][nt] = __builtin_amdgcn_mfma_f32_16x16x32_f16(
                        af[mt], bf[nt], acc[mt][nt], 0, 0, 0);
        }
        __syncthreads();
    }

#pragma unroll
    for (int nt = 0; nt < 4; ++nt) {
        const int n = wn * 64 + nt * 16 + lr;
        const float bv = bias[n];
#pragma unroll
        for (int mt = 0; mt < 2; ++mt) {
#pragma unroll
            for (int r = 0; r < 4; ++r) {
                const int m = mb * 64 + wm * 32 + mt * 16 + q * 4 + r;
                xp[(size_t)m * 128 + n] = acc[mt][nt][r] + bv;
            }
        }
    }
}

// ---------------------------------------------------------------- scan ----
// R7/R11 config: single chain, NCH=8 chunks of CHK=64, HALO=32 ->
// 96 steps/wave, 1024 waves (1/SIMD).
#define CHK  64
#define NCH  8
#define HALO 32

__device__ __forceinline__ float rnn_step(float h, float xcur,
                                          const half2T (&w2)[32])
{
    const float LOG2E2 = 2.885390081777927f;  // 2*log2(e)
    const float hn = __builtin_bit_cast(float,
             __builtin_amdgcn_mov_dpp(__builtin_bit_cast(int, h),
                                      0xB1, 0xF, 0xF, false));
    const int hpi = __builtin_bit_cast(int, __builtin_amdgcn_cvt_pkrtz(h, hn));
    float d[4] = {0.f, 0.f, 0.f, 0.f};
#pragma unroll
    for (int i = 0; i < 32; ++i) {
        const int s = __builtin_amdgcn_readlane(hpi, 2 * i);
        d[i & 3] = __builtin_amdgcn_fdot2(__builtin_bit_cast(half2T, s),
                                          w2[i], d[i & 3], false);
    }
    const float z = xcur + ((d[0] + d[1]) + (d[2] + d[3]));
    const float e = __builtin_amdgcn_exp2f(z * LOG2E2);
    const float r = __builtin_amdgcn_rcpf(1.f + e);
    return __builtin_fmaf(-2.f, r, 1.f);
}

__global__ __launch_bounds__(64) void scan_kernel(
    const float* __restrict__ Whf, const float* __restrict__ Whb,
    const float* __restrict__ xp, float* __restrict__ hs)
{
    const int b   = blockIdx.x;   // 0..63
    const int dir = blockIdx.y;   // 0 fwd, 1 bwd
    const int c   = blockIdx.z;   // chunk 0..7
    const int j   = threadIdx.x;  // 0..63 output unit
    const float* Wr = (dir ? Whb : Whf) + j * 64;

    half2T w2[32];
#pragma unroll
    for (int i = 0; i < 32; ++i) {
        w2[i][0] = (_Float16)Wr[2 * i];
        w2[i][1] = (_Float16)Wr[2 * i + 1];
    }

    const size_t base = (size_t)b * T_LEN * 128 + dir * 64 + j;
    const float* xpp = xp + base;
    float*       hsp = hs + base;

    const int fwd  = (dir == 0);
    const int stp  = fwd ? 1 : -1;
    const int creal0 = c * CHK;
    const int creal1 = c * CHK + CHK - 1;
    int tt = fwd ? (creal0 - HALO) : (creal1 + HALO);

    int tcl = tt < 0 ? 0 : (tt > T_LEN - 1 ? T_LEN - 1 : tt);
    float xcur = xpp[(size_t)tcl * 128];
    float h = 0.f;

    for (int it = 0; it < HALO + CHK; ++it) {
        const int tn = tt + stp;
        const int tc2 = tn < 0 ? 0 : (tn > T_LEN - 1 ? T_LEN - 1 : tn);
        const float xnext = xpp[(size_t)tc2 * 128];

        if (tt >= 0 && tt < T_LEN) {          // wave-uniform predicate
            h = rnn_step(h, xcur, w2);
            if (tt >= creal0 && tt <= creal1)  // store only real region
                hsp[(size_t)tt * 128] = h;
        }
        xcur = xnext;
        tt = tn;
    }
}

// ---------------------------------------------------------------- head ----
__global__ __launch_bounds__(256) void head_kernel(
    const float* __restrict__ hs, const float* __restrict__ W1,
    const float* __restrict__ b1, const float* __restrict__ gamma,
    const float* __restrict__ beta, const float* __restrict__ W2,
    const float* __restrict__ b2, float* __restrict__ out)
{
    __shared__ float4 sW1[32 * 32];            // W1[32][128] as float4
    __shared__ float  sb1[32], sg[32], sbt[32], sW2[4 * 34], sb2[4];

    const int t = threadIdx.x;
    const float4* W1v = (const float4*)W1;
    for (int i = t; i < 1024; i += 256) sW1[i] = W1v[i];
    if (t < 32) { sb1[t] = b1[t]; sg[t] = gamma[t]; sbt[t] = beta[t]; }
    if (t < 128) sW2[(t >> 5) * 34 + (t & 31)] = W2[t];
    if (t < 4)  sb2[t] = b2[t];
    __syncthreads();

    const int m  = blockIdx.x * 64 + (t >> 2);
    const int kg = t & 3;

    const float4* xrow = (const float4*)(hs + (size_t)m * 128);
    float4 xq[8];
#pragma unroll
    for (int c = 0; c < 8; ++c) xq[c] = xrow[c * 4 + kg];

    float h1[32];
#pragma unroll
    for (int jj = 0; jj < 32; ++jj) {
        float a = 0.f;
#pragma unroll
        for (int c = 0; c < 8; ++c) {
            const float4 wv = sW1[jj * 32 + c * 4 + kg];
            a += wv.x * xq[c].x + wv.y * xq[c].y + wv.z * xq[c].z + wv.w * xq[c].w;
        }
        a += __builtin_bit_cast(float,
             __builtin_amdgcn_mov_dpp(__builtin_bit_cast(int, a), 0xB1, 0xF, 0xF, false));
        a += __builtin_bit_cast(float,
             __builtin_amdgcn_mov_dpp(__builtin_bit_cast(int, a), 0x4E, 0xF, 0xF, false));
        h1[jj] = a + sb1[jj];
    }

    float mu = 0.f;
#pragma unroll
    for (int jj = 0; jj < 32; ++jj) mu += h1[jj];
    mu *= (1.f / 32.f);
    float var = 0.f;
#pragma unroll
    for (int jj = 0; jj < 32; ++jj) { const float dlt = h1[jj] - mu; var += dlt * dlt; }
    var *= (1.f / 32.f);
    const float rstd = rsqrtf(var + 1e-5f);

    float acc2 = sb2[kg];
#pragma unroll
    for (int jj = 0; jj < 32; ++jj) {
        const float v = (h1[jj] - mu) * rstd * sg[jj] + sbt[jj];
        const float y = v > 0.f ? v : 0.f;
        acc2 += sW2[kg * 34 + jj] * y;
    }
    out[(size_t)m * 4 + kg] = acc2;
}

// -------------------------------------------------------------- launch ----
extern "C" void kernel_launch(void* const* d_in, const int* in_sizes, int n_in,
                              void* d_out, int out_size, void* d_ws, size_t ws_size,
                              hipStream_t stream)
{
    const float* inputs = (const float*)d_in[0];
    const int*   pos    = (const int*)d_in[1];
    const float* emb    = (const float*)d_in[2];
    const float* Wihf   = (const float*)d_in[3];
    const float* Whhf   = (const float*)d_in[4];
    const float* bihf   = (const float*)d_in[5];
    const float* bhhf   = (const float*)d_in[6];
    const float* Wihb   = (const float*)d_in[7];
    const float* Whhb   = (const float*)d_in[8];
    const float* bihb   = (const float*)d_in[9];
    const float* bhhb   = (const float*)d_in[10];
    const float* W1     = (const float*)d_in[11];
    const float* b1v    = (const float*)d_in[12];
    const float* gam    = (const float*)d_in[13];
    const float* bet    = (const float*)d_in[14];
    const float* W2     = (const float*)d_in[15];
    const float* b2v    = (const float*)d_in[16];

    char* ws = (char*)d_ws;
    _Float16* Wt  = (_Float16*)(ws);
    float* bias   = (float*)(ws + BIAS_OFF);
    float* xp     = (float*)(ws + XP_OFF);
    float* hsbuf  = (float*)(ws + HS_OFF);

    prep_kernel<<<dim3(7, 128), 128, 0, stream>>>(Wihf, Wihb, bihf, bhhf, bihb, bhhb, Wt, bias);
    gemm_kernel<<<dim3(512), 256, 0, stream>>>(inputs, pos, emb, Wt, bias, xp);
    scan_kernel<<<dim3(64, 2, NCH), 64, 0, stream>>>(Whhf, Whhb, xp, hsbuf);
    head_kernel<<<dim3(512), 256, 0, stream>>>(hsbuf, W1, b1v, gam, bet, W2, b2v, (float*)d_out);
}